// Round 6
// baseline (156.320 us; speedup 1.0000x reference)
//
#include <hip/hip_runtime.h>

#define KDIM 64
#define VDIM 64
#define MDIM 2048
#define BDIM 512
#define INDIM 512
#define HDIM 192           // 2K+V
#define CIN 768            // IN + 2K + 2V
#define O_SIZE (BDIM*HDIM) // 98304

// ---------- K1: tiled GEMM  o = [x, relu(h), content] @ W^T + bias ----------
// C[512x192] = inp[512x768] @ W^T.  Tiles: 32(b) x 32(j), K-step 64.
// grid = 16 b-tiles * 6 j-tiles = 96 blocks, 256 threads, 2x2 micro-tile.
__global__ __launch_bounds__(256)
void gemm_kernel(const float* __restrict__ x, const float* __restrict__ hidden,
                 const float* __restrict__ content, const float* __restrict__ W,
                 const float* __restrict__ bias, float* __restrict__ out)
{
    const int tid  = threadIdx.x;
    const int bt   = blockIdx.x & 15;   // b-tile 0..15
    const int jt   = blockIdx.x >> 4;   // j-tile 0..5
    const int tx   = tid & 15;          // micro b
    const int ty   = tid >> 4;          // micro j
    const int lane = tid & 63;
    const int wid  = tid >> 6;

    __shared__ float As[64][34];  // As[k][b_local], stride 34 -> 8B-aligned pairs
    __shared__ float Bs[64][34];  // Bs[k][j_local]

    float acc00 = 0.f, acc01 = 0.f, acc10 = 0.f, acc11 = 0.f;

    for (int k0 = 0; k0 < CIN; k0 += 64) {
        // stage 32x64 of inp (transposed) and W (transposed); wave-uniform source branch
        #pragma unroll
        for (int i = 0; i < 8; ++i) {
            const int r = i*4 + wid;    // 0..31
            const int k = lane;         // 0..63
            const int c = k0 + k;
            const int bg = bt*32 + r;
            float av;
            if (c < INDIM)             av = x[(size_t)bg*INDIM + c];
            else if (c < INDIM + HDIM) av = fmaxf(hidden[(size_t)bg*HDIM + (c - INDIM)], 0.f);
            else                       av = content[(size_t)bg*VDIM + (c - INDIM - HDIM)];
            As[k][r] = av;
            const int jg = jt*32 + r;
            Bs[k][r] = W[(size_t)jg*CIN + c];
        }
        __syncthreads();
        #pragma unroll 16
        for (int k = 0; k < 64; ++k) {
            const float a0 = As[k][tx*2], a1 = As[k][tx*2+1];
            const float b0 = Bs[k][ty*2], b1 = Bs[k][ty*2+1];
            acc00 = fmaf(a0, b0, acc00);
            acc01 = fmaf(a0, b1, acc01);
            acc10 = fmaf(a1, b0, acc10);
            acc11 = fmaf(a1, b1, acc11);
        }
        __syncthreads();
    }

    const int bg = bt*32 + tx*2;
    const int jg = jt*32 + ty*2;
    const float bi0 = bias[jg], bi1 = bias[jg+1];
    out[(size_t)bg*HDIM + jg]           = acc00 + bi0;
    out[(size_t)bg*HDIM + jg + 1]       = acc01 + bi1;
    out[(size_t)(bg+1)*HDIM + jg]       = acc10 + bi0;
    out[(size_t)(bg+1)*HDIM + jg + 1]   = acc11 + bi1;
}

// ---------- K2: fused scores+softmax+pv (round-1 proven structure) ----------
__global__ __launch_bounds__(512, 4)
void attn_kernel(const float* __restrict__ key_mem,
                 const float* __restrict__ value_mem,
                 const float* __restrict__ o,
                 float* __restrict__ out)
{
    const int b    = blockIdx.x;
    const int tid  = threadIdx.x;
    const int lane = tid & 63;
    const int wid  = tid >> 6;

    __shared__ float q[KDIM];
    __shared__ float red[8];
    __shared__ __align__(16) float attn_lds[MDIM]; // 8 KB

    if (tid < KDIM) q[tid] = o[(size_t)b*HDIM + tid];
    __syncthreads();

    // ---- scores: thread owns float4 of m ----
    const float4* km4 = reinterpret_cast<const float4*>(key_mem + (size_t)b*KDIM*MDIM);
    float4 s = make_float4(0.f, 0.f, 0.f, 0.f);
    #pragma unroll 8
    for (int k = 0; k < KDIM; ++k) {
        float qk = q[k];
        float4 kk = km4[(size_t)k*(MDIM/4) + tid];
        s.x = fmaf(qk, kk.x, s.x);
        s.y = fmaf(qk, kk.y, s.y);
        s.z = fmaf(qk, kk.z, s.z);
        s.w = fmaf(qk, kk.w, s.w);
    }

    // ---- block softmax over m ----
    float mx = fmaxf(fmaxf(s.x, s.y), fmaxf(s.z, s.w));
    #pragma unroll
    for (int off = 32; off >= 1; off >>= 1)
        mx = fmaxf(mx, __shfl_xor(mx, off));
    if (lane == 0) red[wid] = mx;
    __syncthreads();
    float m_all = red[0];
    #pragma unroll
    for (int w = 1; w < 8; ++w) m_all = fmaxf(m_all, red[w]);

    float4 e;
    e.x = __expf(s.x - m_all);
    e.y = __expf(s.y - m_all);
    e.z = __expf(s.z - m_all);
    e.w = __expf(s.w - m_all);
    float sum = (e.x + e.y) + (e.z + e.w);
    #pragma unroll
    for (int off = 32; off >= 1; off >>= 1)
        sum += __shfl_xor(sum, off);
    __syncthreads();
    if (lane == 0) red[wid] = sum;
    __syncthreads();
    float total = 0.f;
    #pragma unroll
    for (int w = 0; w < 8; ++w) total += red[w];
    float inv = 1.0f / total;

    reinterpret_cast<float4*>(attn_lds)[tid] =
        make_float4(e.x*inv, e.y*inv, e.z*inv, e.w*inv);
    __syncthreads();

    // ---- pv: wave handles 8 v's; coalesced float4 value loads ----
    const float4* vm4 = reinterpret_cast<const float4*>(value_mem + (size_t)b*VDIM*MDIM);
    const float4* a4  = reinterpret_cast<const float4*>(attn_lds);
    #pragma unroll
    for (int vi = 0; vi < 8; ++vi) {
        int v = wid*8 + vi;
        float px = 0.f, py = 0.f, pz = 0.f, pw = 0.f;
        #pragma unroll
        for (int i = 0; i < 8; ++i) {
            float4 vv = vm4[(size_t)v*(MDIM/4) + i*64 + lane];
            float4 aa = a4[i*64 + lane];
            px = fmaf(vv.x, aa.x, px);
            py = fmaf(vv.y, aa.y, py);
            pz = fmaf(vv.z, aa.z, pz);
            pw = fmaf(vv.w, aa.w, pw);
        }
        float p = (px + py) + (pz + pw);
        #pragma unroll
        for (int off = 32; off >= 1; off >>= 1)
            p += __shfl_xor(p, off);
        if (lane == 0) out[O_SIZE + (size_t)b*VDIM + v] = p;
    }
}

extern "C" void kernel_launch(void* const* d_in, const int* in_sizes, int n_in,
                              void* d_out, int out_size, void* d_ws, size_t ws_size,
                              hipStream_t stream) {
    const float* x         = (const float*)d_in[0];
    const float* hidden    = (const float*)d_in[1];
    const float* content   = (const float*)d_in[2];
    const float* key_mem   = (const float*)d_in[3];
    const float* value_mem = (const float*)d_in[4];
    const float* W         = (const float*)d_in[5];
    const float* bias      = (const float*)d_in[6];
    float* out = (float*)d_out;

    gemm_kernel<<<dim3(96),   dim3(256), 0, stream>>>(x, hidden, content, W, bias, out);
    attn_kernel<<<dim3(BDIM), dim3(512), 0, stream>>>(key_mem, value_mem, out, out);
}

// Round 7
// 135.385 us; speedup vs baseline: 1.1546x; 1.1546x over previous
//
#include <hip/hip_runtime.h>

#define KDIM 64
#define VDIM 64
#define MDIM 2048
#define BDIM 512
#define INDIM 512
#define HDIM 192           // 2K+V
#define CIN 768            // IN + 2K + 2V
#define O_SIZE (BDIM*HDIM) // 98304

// One 1024-thread block per batch row b. 512 blocks x 16 waves = 8192 waves.
__global__ __launch_bounds__(1024, 8)
void memlinear_kernel(const float* __restrict__ x,
                      const float* __restrict__ hidden,
                      const float* __restrict__ content,
                      const float* __restrict__ key_mem,
                      const float* __restrict__ value_mem,
                      const float* __restrict__ W,
                      const float* __restrict__ bias,
                      float* __restrict__ out)
{
    const int b    = blockIdx.x;
    const int tid  = threadIdx.x;
    const int lane = tid & 63;
    const int wid  = tid >> 6;   // 0..15

    __shared__ __align__(16) float inp[CIN];       // 3 KB
    __shared__ float q[KDIM];
    __shared__ float red[16];
    __shared__ __align__(16) float attn_lds[MDIM]; // 8 KB

    // ---- Phase A1: stage concat input (768 of 1024 threads) ----
    if (tid < INDIM) inp[tid] = x[(size_t)b*INDIM + tid];
    else if (tid < INDIM + HDIM) inp[tid] = fmaxf(hidden[(size_t)b*HDIM + (tid - INDIM)], 0.f);
    else if (tid < CIN) inp[tid] = content[(size_t)b*VDIM + (tid - INDIM - HDIM)];
    __syncthreads();

    // ---- Phase A2: o = inp @ W^T + bias, 4 threads per output ----
    if (tid < 4*HDIM) {                               // 768 active
        const int j = tid >> 2;                       // output index
        const int qr = tid & 3;                       // quarter of CIN
        const float4* w4 = reinterpret_cast<const float4*>(W)
                           + (size_t)j * (CIN/4) + qr * (CIN/16);
        const float4* i4 = reinterpret_cast<const float4*>(inp) + qr * (CIN/16);
        float ax = 0.f, ay = 0.f, az = 0.f, aw = 0.f;
        #pragma unroll
        for (int r = 0; r < CIN/16; r += 8) {         // 48 float4, 6 rounds of 8
            float4 wr[8];
            #pragma unroll
            for (int u = 0; u < 8; ++u) wr[u] = w4[r + u];
            #pragma unroll
            for (int u = 0; u < 8; ++u) {
                float4 v = i4[r + u];
                ax = fmaf(wr[u].x, v.x, ax);
                ay = fmaf(wr[u].y, v.y, ay);
                az = fmaf(wr[u].z, v.z, az);
                aw = fmaf(wr[u].w, v.w, aw);
            }
        }
        float p = (ax + ay) + (az + aw);
        p += __shfl_xor(p, 1);                        // combine quarters 0<->1, 2<->3
        p += __shfl_xor(p, 2);                        // combine pairs
        if (qr == 0) {
            float o = p + bias[j];
            out[(size_t)b*HDIM + j] = o;
            if (j < KDIM) q[j] = o;
        }
    }
    __syncthreads();

    // ---- Phase B: scores, thread owns float2 of m (1024 thr x 2 = 2048) ----
    const float2* km2 = reinterpret_cast<const float2*>(key_mem)
                        + (size_t)b * KDIM * (MDIM/2) + tid;
    float sx = 0.f, sy = 0.f;
    #pragma unroll
    for (int k0 = 0; k0 < KDIM; k0 += 8) {
        float2 kk[8];
        #pragma unroll
        for (int u = 0; u < 8; ++u)
            kk[u] = km2[(size_t)(k0 + u) * (MDIM/2)];
        #pragma unroll
        for (int u = 0; u < 8; ++u) {
            float qk = q[k0 + u];
            sx = fmaf(qk, kk[u].x, sx);
            sy = fmaf(qk, kk[u].y, sy);
        }
    }

    // ---- Phase C: softmax (16-wave block reduce) ----
    float mx = fmaxf(sx, sy);
    #pragma unroll
    for (int off = 32; off >= 1; off >>= 1) mx = fmaxf(mx, __shfl_xor(mx, off));
    if (lane == 0) red[wid] = mx;
    __syncthreads();
    float m_all = red[0];
    #pragma unroll
    for (int w = 1; w < 16; ++w) m_all = fmaxf(m_all, red[w]);

    float ex = __expf(sx - m_all);
    float ey = __expf(sy - m_all);
    float sum = ex + ey;
    #pragma unroll
    for (int off = 32; off >= 1; off >>= 1) sum += __shfl_xor(sum, off);
    __syncthreads();                 // red(max) fully consumed
    if (lane == 0) red[wid] = sum;
    __syncthreads();
    float total = 0.f;
    #pragma unroll
    for (int w = 0; w < 16; ++w) total += red[w];
    float inv = 1.0f / total;

    reinterpret_cast<float2*>(attn_lds)[tid] = make_float2(ex*inv, ey*inv);
    __syncthreads();

    // ---- Phase D: pv, wave owns 4 v's; attn row hoisted to registers ----
    const float4* a4 = reinterpret_cast<const float4*>(attn_lds);
    float4 aa[8];
    #pragma unroll
    for (int i = 0; i < 8; ++i) aa[i] = a4[i*64 + lane];

    const float4* vm4 = reinterpret_cast<const float4*>(value_mem)
                        + (size_t)b * VDIM * (MDIM/4);
    #pragma unroll
    for (int vi = 0; vi < 4; ++vi) {
        const int v = wid*4 + vi;
        float4 vv[8];
        #pragma unroll
        for (int i = 0; i < 8; ++i)
            vv[i] = vm4[(size_t)v*(MDIM/4) + i*64 + lane];
        float px = 0.f, py = 0.f, pz = 0.f, pw = 0.f;
        #pragma unroll
        for (int i = 0; i < 8; ++i) {
            px = fmaf(vv[i].x, aa[i].x, px);
            py = fmaf(vv[i].y, aa[i].y, py);
            pz = fmaf(vv[i].z, aa[i].z, pz);
            pw = fmaf(vv[i].w, aa[i].w, pw);
        }
        float p = (px + py) + (pz + pw);
        #pragma unroll
        for (int off = 32; off >= 1; off >>= 1) p += __shfl_xor(p, off);
        if (lane == 0) out[O_SIZE + (size_t)b*VDIM + v] = p;
    }
}

extern "C" void kernel_launch(void* const* d_in, const int* in_sizes, int n_in,
                              void* d_out, int out_size, void* d_ws, size_t ws_size,
                              hipStream_t stream) {
    const float* x         = (const float*)d_in[0];
    const float* hidden    = (const float*)d_in[1];
    const float* content   = (const float*)d_in[2];
    const float* key_mem   = (const float*)d_in[3];
    const float* value_mem = (const float*)d_in[4];
    const float* W         = (const float*)d_in[5];
    const float* bias      = (const float*)d_in[6];
    float* out = (float*)d_out;

    memlinear_kernel<<<dim3(BDIM), dim3(1024), 0, stream>>>(
        x, hidden, content, key_mem, value_mem, W, bias, out);
}

// Round 9
// 120.272 us; speedup vs baseline: 1.2997x; 1.1257x over previous
//
#include <hip/hip_runtime.h>

#define KDIM 64
#define VDIM 64
#define MDIM 2048
#define BDIM 512
#define INDIM 512
#define HDIM 192           // 2K+V
#define CIN 768            // IN + 2K + 2V
#define O_SIZE (BDIM*HDIM) // 98304

typedef float f32x4 __attribute__((ext_vector_type(4)));

__global__ __launch_bounds__(512, 4)
void memlinear_kernel(const float* __restrict__ x,
                      const float* __restrict__ hidden,
                      const float* __restrict__ content,
                      const float* __restrict__ key_mem,
                      const float* __restrict__ value_mem,
                      const float* __restrict__ W,
                      const float* __restrict__ bias,
                      float* __restrict__ out)
{
    const int b    = blockIdx.x;
    const int tid  = threadIdx.x;
    const int lane = tid & 63;
    const int wid  = tid >> 6;

    __shared__ __align__(16) float inp[CIN];       // 3 KB
    __shared__ float q[KDIM];
    __shared__ float red[8];
    __shared__ __align__(16) float attn_lds[MDIM]; // 8 KB

    // ---- Phase A: stage concat input, tiny GEMM o = inp @ W^T + b ----
    if (tid < INDIM) inp[tid] = x[(size_t)b*INDIM + tid];
    if (tid < HDIM)  inp[INDIM + tid] = fmaxf(hidden[(size_t)b*HDIM + tid], 0.f);
    if (tid < VDIM)  inp[INDIM + HDIM + tid] = content[(size_t)b*VDIM + tid];
    __syncthreads();

    if (tid < HDIM) {
        const float4* w4 = reinterpret_cast<const float4*>(W) + (size_t)tid * (CIN/4);
        const float4* i4 = reinterpret_cast<const float4*>(inp);
        float ax = 0.f, ay = 0.f, az = 0.f, aw = 0.f;
        #pragma unroll 8
        for (int i = 0; i < CIN/4; ++i) {
            float4 w = w4[i];
            float4 v = i4[i];
            ax = fmaf(w.x, v.x, ax);
            ay = fmaf(w.y, v.y, ay);
            az = fmaf(w.z, v.z, az);
            aw = fmaf(w.w, v.w, aw);
        }
        float o = (ax + ay) + (az + aw) + bias[tid];
        out[(size_t)b*HDIM + tid] = o;
        if (tid < KDIM) q[tid] = o;
    }
    __syncthreads();

    // ---- Phase B: scores[m] = sum_k key_mem[b,k,m] * q[k], 4 m's/thread ----
    // key_mem streamed once per call: non-temporal (bypass cache insert).
    const f32x4* km4 = reinterpret_cast<const f32x4*>(key_mem + (size_t)b*KDIM*MDIM);
    float sx = 0.f, sy = 0.f, sz = 0.f, sw = 0.f;
    #pragma unroll 8
    for (int k = 0; k < KDIM; ++k) {
        float qk = q[k];
        f32x4 kk = __builtin_nontemporal_load(km4 + (size_t)k*(MDIM/4) + tid);
        sx = fmaf(qk, kk.x, sx);
        sy = fmaf(qk, kk.y, sy);
        sz = fmaf(qk, kk.z, sz);
        sw = fmaf(qk, kk.w, sw);
    }

    // ---- Phase C: block softmax over m ----
    float mx = fmaxf(fmaxf(sx, sy), fmaxf(sz, sw));
    #pragma unroll
    for (int off = 32; off >= 1; off >>= 1)
        mx = fmaxf(mx, __shfl_xor(mx, off));
    if (lane == 0) red[wid] = mx;
    __syncthreads();
    float m_all = red[0];
    #pragma unroll
    for (int w = 1; w < 8; ++w) m_all = fmaxf(m_all, red[w]);

    float ex = __expf(sx - m_all);
    float ey = __expf(sy - m_all);
    float ez = __expf(sz - m_all);
    float ew = __expf(sw - m_all);
    float sum = (ex + ey) + (ez + ew);
    #pragma unroll
    for (int off = 32; off >= 1; off >>= 1)
        sum += __shfl_xor(sum, off);
    __syncthreads();                 // everyone done reading red (max)
    if (lane == 0) red[wid] = sum;
    __syncthreads();
    float total = 0.f;
    #pragma unroll
    for (int w = 0; w < 8; ++w) total += red[w];
    float inv = 1.0f / total;

    reinterpret_cast<float4*>(attn_lds)[tid] =
        make_float4(ex*inv, ey*inv, ez*inv, ew*inv);
    __syncthreads();

    // ---- Phase D: content_new[v] = sum_m value_mem[b,v,m] * attn[m] ----
    // value_mem streamed once per call: non-temporal.
    const f32x4* vm4 = reinterpret_cast<const f32x4*>(value_mem + (size_t)b*VDIM*MDIM);
    const float4* a4 = reinterpret_cast<const float4*>(attn_lds);
    #pragma unroll
    for (int vi = 0; vi < 8; ++vi) {
        int v = wid*8 + vi;
        float px = 0.f, py = 0.f, pz = 0.f, pw = 0.f;
        #pragma unroll
        for (int i = 0; i < 8; ++i) {
            f32x4 vv = __builtin_nontemporal_load(vm4 + (size_t)v*(MDIM/4) + i*64 + lane);
            float4 aa = a4[i*64 + lane];
            px = fmaf(vv.x, aa.x, px);
            py = fmaf(vv.y, aa.y, py);
            pz = fmaf(vv.z, aa.z, pz);
            pw = fmaf(vv.w, aa.w, pw);
        }
        float p = (px + py) + (pz + pw);
        #pragma unroll
        for (int off = 32; off >= 1; off >>= 1)
            p += __shfl_xor(p, off);
        if (lane == 0) out[O_SIZE + (size_t)b*VDIM + v] = p;
    }
}

extern "C" void kernel_launch(void* const* d_in, const int* in_sizes, int n_in,
                              void* d_out, int out_size, void* d_ws, size_t ws_size,
                              hipStream_t stream) {
    const float* x         = (const float*)d_in[0];
    const float* hidden    = (const float*)d_in[1];
    const float* content   = (const float*)d_in[2];
    const float* key_mem   = (const float*)d_in[3];
    const float* value_mem = (const float*)d_in[4];
    const float* W         = (const float*)d_in[5];
    const float* bias      = (const float*)d_in[6];
    float* out = (float*)d_out;

    memlinear_kernel<<<dim3(BDIM), dim3(512), 0, stream>>>(
        x, hidden, content, key_mem, value_mem, W, bias, out);
}

// Round 10
// 116.418 us; speedup vs baseline: 1.3427x; 1.0331x over previous
//
#include <hip/hip_runtime.h>

#define KDIM 64
#define VDIM 64
#define MDIM 2048
#define BDIM 512
#define INDIM 512
#define HDIM 192           // 2K+V
#define CIN 768            // IN + 2K + 2V
#define O_SIZE (BDIM*HDIM) // 98304

typedef float f32x4 __attribute__((ext_vector_type(4)));

__global__ __launch_bounds__(512, 4)
void memlinear_kernel(const float* __restrict__ x,
                      const float* __restrict__ hidden,
                      const float* __restrict__ content,
                      const float* __restrict__ key_mem,
                      const float* __restrict__ value_mem,
                      const float* __restrict__ W,
                      const float* __restrict__ bias,
                      float* __restrict__ out)
{
    const int b    = blockIdx.x;
    const int tid  = threadIdx.x;
    const int lane = tid & 63;
    const int wid  = tid >> 6;

    __shared__ __align__(16) float inp[CIN];       // 3 KB
    __shared__ float q[KDIM];
    __shared__ float red[8];
    __shared__ __align__(16) float attn_lds[MDIM]; // 8 KB

    // ---- Phase A1: stage concat input ----
    if (tid < INDIM) inp[tid] = x[(size_t)b*INDIM + tid];
    if (tid < HDIM)  inp[INDIM + tid] = fmaxf(hidden[(size_t)b*HDIM + tid], 0.f);
    if (tid < VDIM)  inp[INDIM + HDIM + tid] = content[(size_t)b*VDIM + tid];
    __syncthreads();

    // ---- Phase A2: q only (o[:,:64]), 8 threads per output -> short prologue ----
    {
        const int j = tid >> 3;        // 0..63
        const int p = tid & 7;         // part
        const float4* w4 = reinterpret_cast<const float4*>(W)
                           + (size_t)j * (CIN/4) + p * (CIN/32);
        const float4* i4 = reinterpret_cast<const float4*>(inp) + p * (CIN/32);
        float ax = 0.f, ay = 0.f, az = 0.f, aw = 0.f;
        #pragma unroll
        for (int r = 0; r < CIN/32; r += 8) {      // 24 float4, 3 rounds of 8
            float4 wr[8];
            #pragma unroll
            for (int u = 0; u < 8; ++u) wr[u] = w4[r + u];
            #pragma unroll
            for (int u = 0; u < 8; ++u) {
                float4 v = i4[r + u];
                ax = fmaf(wr[u].x, v.x, ax);
                ay = fmaf(wr[u].y, v.y, ay);
                az = fmaf(wr[u].z, v.z, az);
                aw = fmaf(wr[u].w, v.w, aw);
            }
        }
        float pacc = (ax + ay) + (az + aw);
        pacc += __shfl_xor(pacc, 1);
        pacc += __shfl_xor(pacc, 2);
        pacc += __shfl_xor(pacc, 4);
        if (p == 0) {
            float o = pacc + bias[j];
            out[(size_t)b*HDIM + j] = o;
            q[j] = o;
        }
    }
    __syncthreads();

    // ---- Phase B: scores[m] = sum_k key_mem[b,k,m]*q[k], 4 m's/thread, NT ----
    const f32x4* km4 = reinterpret_cast<const f32x4*>(key_mem + (size_t)b*KDIM*MDIM);
    float sx = 0.f, sy = 0.f, sz = 0.f, sw = 0.f;
    #pragma unroll 8
    for (int k = 0; k < KDIM; ++k) {
        float qk = q[k];
        f32x4 kk = __builtin_nontemporal_load(km4 + (size_t)k*(MDIM/4) + tid);
        sx = fmaf(qk, kk.x, sx);
        sy = fmaf(qk, kk.y, sy);
        sz = fmaf(qk, kk.z, sz);
        sw = fmaf(qk, kk.w, sw);
    }

    // ---- Phase C: block softmax over m ----
    float mx = fmaxf(fmaxf(sx, sy), fmaxf(sz, sw));
    #pragma unroll
    for (int off = 32; off >= 1; off >>= 1)
        mx = fmaxf(mx, __shfl_xor(mx, off));
    if (lane == 0) red[wid] = mx;
    __syncthreads();
    float m_all = red[0];
    #pragma unroll
    for (int w = 1; w < 8; ++w) m_all = fmaxf(m_all, red[w]);

    float ex = __expf(sx - m_all);
    float ey = __expf(sy - m_all);
    float ez = __expf(sz - m_all);
    float ew = __expf(sw - m_all);
    float sum = (ex + ey) + (ez + ew);
    #pragma unroll
    for (int off = 32; off >= 1; off >>= 1)
        sum += __shfl_xor(sum, off);
    __syncthreads();
    if (lane == 0) red[wid] = sum;
    __syncthreads();
    float total = 0.f;
    #pragma unroll
    for (int w = 0; w < 8; ++w) total += red[w];
    float inv = 1.0f / total;

    reinterpret_cast<float4*>(attn_lds)[tid] =
        make_float4(ex*inv, ey*inv, ez*inv, ew*inv);
    __syncthreads();

    // ---- Phase D: content_new[v] = sum_m value_mem[b,v,m]*attn[m], NT ----
    const f32x4* vm4 = reinterpret_cast<const f32x4*>(value_mem + (size_t)b*VDIM*MDIM);
    const float4* a4 = reinterpret_cast<const float4*>(attn_lds);
    #pragma unroll
    for (int vi = 0; vi < 8; ++vi) {
        int v = wid*8 + vi;
        float px = 0.f, py = 0.f, pz = 0.f, pw = 0.f;
        #pragma unroll
        for (int i = 0; i < 8; ++i) {
            f32x4 vv = __builtin_nontemporal_load(vm4 + (size_t)v*(MDIM/4) + i*64 + lane);
            float4 aa = a4[i*64 + lane];
            px = fmaf(vv.x, aa.x, px);
            py = fmaf(vv.y, aa.y, py);
            pz = fmaf(vv.z, aa.z, pz);
            pw = fmaf(vv.w, aa.w, pw);
        }
        float p = (px + py) + (pz + pw);
        #pragma unroll
        for (int off = 32; off >= 1; off >>= 1)
            p += __shfl_xor(p, off);
        if (lane == 0) out[O_SIZE + (size_t)b*VDIM + v] = p;
    }

    // ---- Phase E (tail): remaining outputs o[:,64:192], 4 threads/output ----
    {
        const int jj = tid >> 2;       // 0..127
        const int j  = KDIM + jj;      // 64..191
        const int p  = tid & 3;
        const float4* w4 = reinterpret_cast<const float4*>(W)
                           + (size_t)j * (CIN/4) + p * (CIN/16);
        const float4* i4 = reinterpret_cast<const float4*>(inp) + p * (CIN/16);
        float ax = 0.f, ay = 0.f, az = 0.f, aw = 0.f;
        #pragma unroll
        for (int r = 0; r < CIN/16; r += 8) {      // 48 float4, 6 rounds of 8
            float4 wr[8];
            #pragma unroll
            for (int u = 0; u < 8; ++u) wr[u] = w4[r + u];
            #pragma unroll
            for (int u = 0; u < 8; ++u) {
                float4 v = i4[r + u];
                ax = fmaf(wr[u].x, v.x, ax);
                ay = fmaf(wr[u].y, v.y, ay);
                az = fmaf(wr[u].z, v.z, az);
                aw = fmaf(wr[u].w, v.w, aw);
            }
        }
        float pacc = (ax + ay) + (az + aw);
        pacc += __shfl_xor(pacc, 1);
        pacc += __shfl_xor(pacc, 2);
        if (p == 0) out[(size_t)b*HDIM + j] = pacc + bias[j];
    }
}

extern "C" void kernel_launch(void* const* d_in, const int* in_sizes, int n_in,
                              void* d_out, int out_size, void* d_ws, size_t ws_size,
                              hipStream_t stream) {
    const float* x         = (const float*)d_in[0];
    const float* hidden    = (const float*)d_in[1];
    const float* content   = (const float*)d_in[2];
    const float* key_mem   = (const float*)d_in[3];
    const float* value_mem = (const float*)d_in[4];
    const float* W         = (const float*)d_in[5];
    const float* bias      = (const float*)d_in[6];
    float* out = (float*)d_out;

    memlinear_kernel<<<dim3(BDIM), dim3(512), 0, stream>>>(
        x, hidden, content, key_mem, value_mem, W, bias, out);
}